// Round 14
// baseline (251.914 us; speedup 1.0000x reference)
//
#include <hip/hip_runtime.h>
#include <hip/hip_bf16.h>
#include <math.h>

#define CNUM 20
#define KNUM 64
#define DDIM 256
#define NHB 64

typedef __attribute__((ext_vector_type(8))) short short8;
typedef __attribute__((ext_vector_type(4))) unsigned short u16x4;
typedef __attribute__((ext_vector_type(4))) float f32x4;

static __device__ __forceinline__ float shfl_xor_f(float v, int m) {
    return __shfl_xor(v, m, 64);
}

static __device__ __forceinline__ unsigned short f2bf(float f) {
    union { float f; unsigned u; } x; x.f = f;
    unsigned r = x.u + 0x7FFF + ((x.u >> 16) & 1);   // RTN-even
    return (unsigned short)(r >> 16);
}

// ---- K_A: fused setup. blocks [0,320): per-(c,k) stats + mu->bf16 (4 ck/block);
// ----      blocks [320,384): label histogram (grid-stride). Block 0 zeroes dcnt. ----
__global__ void k_setup(const float* __restrict__ mu, const float* __restrict__ exp_temp,
                        const float* __restrict__ runa, const float* __restrict__ runb,
                        const float* __restrict__ med, const float* __restrict__ stdv,
                        const int* __restrict__ labels, int N,
                        float* __restrict__ mu2, float* __restrict__ rtau,
                        float* __restrict__ ltau, float* __restrict__ vldf,
                        float* __restrict__ rstd, float* __restrict__ mrs,
                        unsigned short* __restrict__ mubf, int* __restrict__ bc,
                        int* __restrict__ dcnt)
{
    __shared__ int h[CNUM];
    const int bid = blockIdx.x, tid = threadIdx.x;
    if (bid < 320) {
        const int w = tid >> 6, lane = tid & 63;
        if (bid == 0) {
            const float r = 1.0f / stdv[tid];           // blockDim==DDIM==256
            rstd[tid] = r;
            mrs[tid] = med[tid] * r;
            if (tid == 0) *dcnt = 0;                    // ws is poisoned; reset each launch
        }
        const int ck = bid * 4 + w;                      // covers [0, 1280)
        const float4 v = *(const float4*)(mu + (size_t)ck * DDIM + lane * 4);
        u16x4 pk;
        pk[0] = f2bf(v.x); pk[1] = f2bf(v.y); pk[2] = f2bf(v.z); pk[3] = f2bf(v.w);
        *(u16x4*)(mubf + (size_t)ck * DDIM + lane * 4) = pk;
        float s = v.x * v.x + v.y * v.y + v.z * v.z + v.w * v.w;
#pragma unroll
        for (int off = 32; off > 0; off >>= 1) s += shfl_xor_f(s, off);
        if (lane == 0) {
            mu2[ck] = s;
            const float e = exp_temp[ck];
            const float t = 100.0f / (1.0f + __expf(-0.5f * e)) + 0.01f;
            rtau[ck] = 1.0f / t;
            ltau[ck] = logf(t);
            const int c = ck >> 6;
            const float thr = runb[c] * (0.5f / (float)KNUM);
            vldf[ck] = (runa[ck] > thr) ? 1.0f : 0.0f;
        }
    } else {
        const int hb = bid - 320;
        if (tid < CNUM) h[tid] = 0;
        __syncthreads();
        for (int i = hb * 256 + tid; i < N; i += NHB * 256)
            atomicAdd(&h[labels[i]], 1);
        __syncthreads();
        if (tid < CNUM) bc[hb * CNUM + tid] = h[tid];
    }
}

// ---- K_B: scatter with parallel self-computed bases (2-level segment sums);
// ----      block 0 publishes cnt / ps / blk2cls ----
__global__ void k_scatter(const int* __restrict__ labels, int N,
                          const int* __restrict__ bc, int* __restrict__ cnt,
                          int* __restrict__ ps, int* __restrict__ blk2cls,
                          int* __restrict__ idx)
{
    __shared__ int part[8][CNUM];                        // 8 segments of 8 blocks
    __shared__ int clsc[CNUM];
    __shared__ int psl[CNUM + 1];
    __shared__ int cur[CNUM];
    const int tid = threadIdx.x, hb = blockIdx.x;
    if (tid < 8 * CNUM) {
        const int c = tid % CNUM, s = tid / CNUM;
        int v = 0;
#pragma unroll
        for (int j = 0; j < 8; ++j) v += bc[(8 * s + j) * CNUM + c];
        part[s][c] = v;
    }
    __syncthreads();
    if (tid < CNUM) {
        int v = 0;
#pragma unroll
        for (int s = 0; s < 8; ++s) v += part[s][tid];
        clsc[tid] = v;
    }
    __syncthreads();
    if (tid == 0) {
        int run = 0;
        for (int c = 0; c < CNUM; ++c) { psl[c] = run; run += (clsc[c] + 63) & ~63; }
        psl[CNUM] = run;
    }
    __syncthreads();
    if (tid < CNUM) {
        const int full = hb >> 3, rem = hb & 7;
        int before = 0;
        for (int s = 0; s < full; ++s) before += part[s][tid];
        for (int j = 0; j < rem; ++j) before += bc[(8 * full + j) * CNUM + tid];
        cur[tid] = psl[tid] + before;
        if (hb == 0) {
            cnt[tid] = clsc[tid];
            ps[tid] = psl[tid];
            if (tid == 0) ps[CNUM] = psl[CNUM];
            const int b0 = psl[tid] >> 6, b1 = psl[tid + 1] >> 6;
            for (int b = b0; b < b1; ++b) blk2cls[b] = tid;
        }
    }
    __syncthreads();
    for (int i = hb * 256 + tid; i < N; i += NHB * 256) {
        const int c = labels[i];
        const int p = atomicAdd(&cur[c], 1);
        idx[p] = i;
    }
}

// ---- K_C: main — 16-deep batched X gather, LDS constants, LDS mu tile via
// ----      gload_lds; MFMA + softmax; fused deterministic final reduce ----
__global__ __launch_bounds__(256, 3)
void k_main(const float* __restrict__ data, const unsigned short* __restrict__ mubf,
            const float* __restrict__ mrs, const float* __restrict__ rstd,
            const float* __restrict__ mu2, const float* __restrict__ rtau,
            const float* __restrict__ ltau, const float* __restrict__ vldf,
            const int* __restrict__ idx, const int* __restrict__ ps,
            const int* __restrict__ cnt, const int* __restrict__ blk2cls,
            float* __restrict__ wpart, int* __restrict__ dcnt,
            float* __restrict__ out)
{
    __shared__ float cst[512];                           // mrs[256] | rstd[256]
    __shared__ __align__(16) unsigned char Ub[64 * 512]; // bf16 mu tile, swizzled
    __shared__ float redbuf[240];
    __shared__ float segf[CNUM];
    __shared__ int amLast;
    const int tid = threadIdx.x, w = tid >> 6, lane = tid & 63;
    const int g = blockIdx.x;
    const int slot0 = g * 64;
    const int padtot = ps[CNUM];

    if (slot0 < padtot) {
        const int c = blk2cls[g];
        const int relast = ps[c] + cnt[c] - 1;

        cst[tid] = mrs[tid];                             // blockDim==256==DDIM
        cst[256 + tid] = rstd[tid];
        const int n16 = lane & 15, kg = lane >> 4;
        const int slot = slot0 + 16 * w + n16;
        const int n = idx[min(slot, relast)];            // pads duplicate a real row
        __syncthreads();                                 // cst ready

        // ---- X: one batch of 16 independent float4 loads (256B/lane in flight) ----
        const float* __restrict__ xr = data + (size_t)n * DDIM + 8 * kg;
        float4 u[16];
#pragma unroll
        for (int s = 0; s < 8; ++s) {
            u[2 * s]     = *(const float4*)(xr + 32 * s);
            u[2 * s + 1] = *(const float4*)(xr + 32 * s + 4);
        }
        // ---- stage class-mu tile: 8 gload_lds per wave (issued after X batch) ----
        const int h2 = lane >> 5;
        const int m31b = 16 * (lane & 31);
#pragma unroll
        for (int pr = 0; pr < 8; ++pr) {
            const int lr = 16 * w + 2 * pr + h2;         // local mu row 0..63
            const int sw = 16 * (lr & 7);
            const unsigned char* sm = (const unsigned char*)mubf
                + ((size_t)c * KNUM + lr) * 512 + (m31b ^ sw);   // pre-swizzled source
            void* dm = (void*)(Ub + (size_t)(16 * w + 2 * pr) * 512);  // linear dest
            __builtin_amdgcn_global_load_lds(
                (const __attribute__((address_space(1))) void*)sm,
                (__attribute__((address_space(3))) void*)dm, 16, 0, 0);
        }

        // ---- normalize + pack (progressive waits on u[]; mu staging in flight) ----
        const float* __restrict__ cm = &cst[8 * kg];
        const float* __restrict__ cr = &cst[256 + 8 * kg];
        short8 xb[8];
        float q = 0.f;
#pragma unroll
        for (int s = 0; s < 8; ++s) {
            const float4 u0 = u[2 * s], u1 = u[2 * s + 1];
            const float4 m0 = *(const float4*)(cm + 32 * s);
            const float4 m1 = *(const float4*)(cm + 32 * s + 4);
            const float4 r0 = *(const float4*)(cr + 32 * s);
            const float4 r1 = *(const float4*)(cr + 32 * s + 4);
            float a[8];
            a[0] = fmaf(u0.x, r0.x, -m0.x); a[1] = fmaf(u0.y, r0.y, -m0.y);
            a[2] = fmaf(u0.z, r0.z, -m0.z); a[3] = fmaf(u0.w, r0.w, -m0.w);
            a[4] = fmaf(u1.x, r1.x, -m1.x); a[5] = fmaf(u1.y, r1.y, -m1.y);
            a[6] = fmaf(u1.z, r1.z, -m1.z); a[7] = fmaf(u1.w, r1.w, -m1.w);
            union { short8 s8; __hip_bfloat162 b2[4]; } pk;
#pragma unroll
            for (int j = 0; j < 4; ++j) {
                q = fmaf(a[2 * j], a[2 * j], q);
                q = fmaf(a[2 * j + 1], a[2 * j + 1], q);
                pk.b2[j] = __float22bfloat162_rn(float2{a[2 * j], a[2 * j + 1]});
            }
            xb[s] = pk.s8;
        }
        q += shfl_xor_f(q, 16);
        q += shfl_xor_f(q, 32);
        __syncthreads();                                 // drains gload_lds; Ub ready

        // ---- MFMA: A = mu rows (k) from LDS, B = x; C[k][sample] ----
        const int Sb = 16 * (n16 & 7);
        f32x4 acc[4] = {};
#pragma unroll
        for (int s = 0; s < 8; ++s) {
            short8 af[4];
#pragma unroll
            for (int f = 0; f < 4; ++f)
                af[f] = *(const short8*)(Ub + (size_t)(16 * f + n16) * 512
                                            + ((64 * s + 16 * kg) ^ Sb));
#pragma unroll
            for (int f = 0; f < 4; ++f)
                acc[f] = __builtin_amdgcn_mfma_f32_16x16x32_bf16(af[f], xb[s], acc[f], 0, 0, 0);
        }

        // ---- epilogue: lane holds 16 k-values (k = 16f + 4kg + r) of its sample ----
        const int ckb = c * KNUM;
        float simv[16], lpv[16];
        float mxv = -3.4e38f;
#pragma unroll
        for (int f = 0; f < 4; ++f) {
            const int kb = ckb + 16 * f + 4 * kg;
            const float4 m2v = *(const float4*)(mu2 + kb);
            const float4 rtv = *(const float4*)(rtau + kb);
            const float4 ltv = *(const float4*)(ltau + kb);
            const float4 vlv = *(const float4*)(vldf + kb);
#pragma unroll
            for (int r = 0; r < 4; ++r) {
                const float m2 = (&m2v.x)[r];
                const float d2 = fmaxf(fmaf(-2.0f, acc[f][r], q + m2), 0.f);
                const float dist = -6.25f * sqrtf(d2);   // 100/sqrt(256)
                const float sim = ((&vlv.x)[r] > 0.5f) ? dist : -1.0e12f;
                simv[4 * f + r] = sim;
                lpv[4 * f + r] = fmaf(sim, (&rtv.x)[r], -(&ltv.x)[r]);
                mxv = fmaxf(mxv, 0.5f * sim);
            }
        }
        mxv = fmaxf(mxv, shfl_xor_f(mxv, 16));
        mxv = fmaxf(mxv, shfl_xor_f(mxv, 32));
        float se = 0.f, sl = 0.f;
#pragma unroll
        for (int i = 0; i < 16; ++i) {
            const float e = __expf(fmaf(0.5f, simv[i], -mxv));
            se += e;
            sl = fmaf(e, lpv[i], sl);
        }
        se += shfl_xor_f(se, 16); se += shfl_xor_f(se, 32);
        sl += shfl_xor_f(sl, 16); sl += shfl_xor_f(sl, 32);
        float res = (kg == 0 && slot <= relast) ? (-sl / se) : 0.f;
        res += shfl_xor_f(res, 1);
        res += shfl_xor_f(res, 2);
        res += shfl_xor_f(res, 4);
        res += shfl_xor_f(res, 8);
        if (lane == 0) wpart[g * 4 + w] = res;
    } else {
        if (lane == 0) wpart[g * 4 + w] = 0.f;
    }

    // ---- done-counter: last block performs the deterministic final reduce ----
    __threadfence();                                     // publish wpart
    if (tid == 0) {
        const int d = atomicAdd(dcnt, 1);
        amLast = (d == (int)gridDim.x - 1);
    }
    __syncthreads();
    if (!amLast) return;
    if (tid == 0) *dcnt = 0;                             // reset for next replay
    __threadfence();                                     // acquire: see all wpart
    if (tid < 240) {
        const int c = tid / 12, j = tid % 12;
        float s = 0.f;
        const int b0 = ps[c] >> 6, b1 = ps[c + 1] >> 6;
        for (int b = b0 + j; b < b1; b += 12) {
            const float4 v = *(const float4*)(wpart + 4 * b);
            s += ((v.x + v.y) + (v.z + v.w));
        }
        redbuf[tid] = s;
    }
    __syncthreads();
    if (tid < CNUM) {
        float s = 0.f;
#pragma unroll
        for (int j = 0; j < 12; ++j) s += redbuf[tid * 12 + j];
        segf[tid] = s;
    }
    __syncthreads();
    if (tid == 0) {
        float loss = 0.f;
        for (int c = 0; c < CNUM; c++) {
            const float cc = (float)cnt[c];
            if (cc > 0.f) loss += segf[c] / fmaxf(cc, 1.0f);
        }
        out[0] = loss;
    }
}

extern "C" void kernel_launch(void* const* d_in, const int* in_sizes, int n_in,
                              void* d_out, int out_size, void* d_ws, size_t ws_size,
                              hipStream_t stream)
{
    const float* data     = (const float*)d_in[0];
    const int*   labels   = (const int*)d_in[1];
    const float* mu       = (const float*)d_in[2];
    const float* exp_temp = (const float*)d_in[3];
    const float* med      = (const float*)d_in[4];
    const float* stdv     = (const float*)d_in[5];
    const float* runa     = (const float*)d_in[6];
    const float* runb     = (const float*)d_in[7];
    float* out = (float*)d_out;
    const int N = in_sizes[0] / DDIM;
    const int idx_slots = N + CNUM * 64;
    const int NB = (idx_slots + 63) / 64;

    char* w = (char*)d_ws;
    float* mu2  = (float*)w; w += (size_t)CNUM * KNUM * 4;
    float* rtau = (float*)w; w += (size_t)CNUM * KNUM * 4;
    float* ltau = (float*)w; w += (size_t)CNUM * KNUM * 4;
    float* vldf = (float*)w; w += (size_t)CNUM * KNUM * 4;
    float* rstd = (float*)w; w += (size_t)DDIM * 4;
    float* mrs  = (float*)w; w += (size_t)DDIM * 4;
    unsigned short* mubf = (unsigned short*)w; w += (size_t)CNUM * KNUM * DDIM * 2;
    int* bc  = (int*)w; w += (size_t)NHB * CNUM * 4;
    int* cnt = (int*)w; w += 64 * 4;
    int* ps  = (int*)w; w += 64 * 4;
    int* dcnt = (int*)w; w += 64 * 4;
    int* idx = (int*)w; w += (size_t)idx_slots * 4;
    int* blk2cls = (int*)w; w += (size_t)NB * 4;
    float* wp = (float*)w; w += (size_t)NB * 4 * 4;

    k_setup<<<dim3(384), dim3(256), 0, stream>>>(
        mu, exp_temp, runa, runb, med, stdv, labels, N,
        mu2, rtau, ltau, vldf, rstd, mrs, mubf, bc, dcnt);
    k_scatter<<<dim3(NHB), dim3(256), 0, stream>>>(labels, N, bc, cnt, ps, blk2cls, idx);
    k_main<<<dim3(NB), dim3(256), 0, stream>>>(
        data, mubf, mrs, rstd, mu2, rtau, ltau, vldf, idx, ps, cnt, blk2cls,
        wp, dcnt, out);
}

// Round 15
// 53.382 us; speedup vs baseline: 4.7190x; 4.7190x over previous
//
#include <hip/hip_runtime.h>
#include <hip/hip_bf16.h>
#include <math.h>

#define CNUM 20
#define KNUM 64
#define DDIM 256
#define NHB 64

typedef __attribute__((ext_vector_type(8))) short short8;
typedef __attribute__((ext_vector_type(4))) unsigned short u16x4;
typedef __attribute__((ext_vector_type(4))) float f32x4;

static __device__ __forceinline__ float shfl_xor_f(float v, int m) {
    return __shfl_xor(v, m, 64);
}

static __device__ __forceinline__ unsigned short f2bf(float f) {
    union { float f; unsigned u; } x; x.f = f;
    unsigned r = x.u + 0x7FFF + ((x.u >> 16) & 1);   // RTN-even
    return (unsigned short)(r >> 16);
}

// ---- K_A: fused setup. blocks [0,320): per-(c,k) stats + mu->bf16 (4 ck/block);
// ----      blocks [320,384): label histogram (grid-stride) ----
__global__ void k_setup(const float* __restrict__ mu, const float* __restrict__ exp_temp,
                        const float* __restrict__ runa, const float* __restrict__ runb,
                        const float* __restrict__ med, const float* __restrict__ stdv,
                        const int* __restrict__ labels, int N,
                        float* __restrict__ mu2, float* __restrict__ rtau,
                        float* __restrict__ ltau, float* __restrict__ vldf,
                        float* __restrict__ rstd, float* __restrict__ mrs,
                        unsigned short* __restrict__ mubf, int* __restrict__ bc)
{
    __shared__ int h[CNUM];
    const int bid = blockIdx.x, tid = threadIdx.x;
    if (bid < 320) {
        const int w = tid >> 6, lane = tid & 63;
        if (bid == 0) {
            const float r = 1.0f / stdv[tid];           // blockDim==DDIM==256
            rstd[tid] = r;
            mrs[tid] = med[tid] * r;
        }
        const int ck = bid * 4 + w;                      // covers [0, 1280)
        const float4 v = *(const float4*)(mu + (size_t)ck * DDIM + lane * 4);
        u16x4 pk;
        pk[0] = f2bf(v.x); pk[1] = f2bf(v.y); pk[2] = f2bf(v.z); pk[3] = f2bf(v.w);
        *(u16x4*)(mubf + (size_t)ck * DDIM + lane * 4) = pk;
        float s = v.x * v.x + v.y * v.y + v.z * v.z + v.w * v.w;
#pragma unroll
        for (int off = 32; off > 0; off >>= 1) s += shfl_xor_f(s, off);
        if (lane == 0) {
            mu2[ck] = s;
            const float e = exp_temp[ck];
            const float t = 100.0f / (1.0f + __expf(-0.5f * e)) + 0.01f;
            rtau[ck] = 1.0f / t;
            ltau[ck] = logf(t);
            const int c = ck >> 6;
            const float thr = runb[c] * (0.5f / (float)KNUM);
            vldf[ck] = (runa[ck] > thr) ? 1.0f : 0.0f;
        }
    } else {
        const int hb = bid - 320;
        if (tid < CNUM) h[tid] = 0;
        __syncthreads();
        for (int i = hb * 256 + tid; i < N; i += NHB * 256)
            atomicAdd(&h[labels[i]], 1);
        __syncthreads();
        if (tid < CNUM) bc[hb * CNUM + tid] = h[tid];
    }
}

// ---- K_B: scatter with parallel self-computed bases (2-level segment sums);
// ----      block 0 publishes cnt / ps / blk2cls ----
__global__ void k_scatter(const int* __restrict__ labels, int N,
                          const int* __restrict__ bc, int* __restrict__ cnt,
                          int* __restrict__ ps, int* __restrict__ blk2cls,
                          int* __restrict__ idx)
{
    __shared__ int part[8][CNUM];                        // 8 segments of 8 blocks
    __shared__ int clsc[CNUM];
    __shared__ int psl[CNUM + 1];
    __shared__ int cur[CNUM];
    const int tid = threadIdx.x, hb = blockIdx.x;
    if (tid < 8 * CNUM) {
        const int c = tid % CNUM, s = tid / CNUM;
        int v = 0;
#pragma unroll
        for (int j = 0; j < 8; ++j) v += bc[(8 * s + j) * CNUM + c];
        part[s][c] = v;
    }
    __syncthreads();
    if (tid < CNUM) {
        int v = 0;
#pragma unroll
        for (int s = 0; s < 8; ++s) v += part[s][tid];
        clsc[tid] = v;
    }
    __syncthreads();
    if (tid == 0) {
        int run = 0;
        for (int c = 0; c < CNUM; ++c) { psl[c] = run; run += (clsc[c] + 63) & ~63; }
        psl[CNUM] = run;
    }
    __syncthreads();
    if (tid < CNUM) {
        const int full = hb >> 3, rem = hb & 7;
        int before = 0;
        for (int s = 0; s < full; ++s) before += part[s][tid];
        for (int j = 0; j < rem; ++j) before += bc[(8 * full + j) * CNUM + tid];
        cur[tid] = psl[tid] + before;
        if (hb == 0) {
            cnt[tid] = clsc[tid];
            ps[tid] = psl[tid];
            if (tid == 0) ps[CNUM] = psl[CNUM];
            const int b0 = psl[tid] >> 6, b1 = psl[tid + 1] >> 6;
            for (int b = b0; b < b1; ++b) blk2cls[b] = tid;
        }
    }
    __syncthreads();
    for (int i = hb * 256 + tid; i < N; i += NHB * 256) {
        const int c = labels[i];
        const int p = atomicAdd(&cur[c], 1);
        idx[p] = i;
    }
}

// ---- K_C: main — R13-verbatim. LDS mu tile via gload_lds, 16-deep batched X
// ----      gather, explicit vmcnt(0) (pins the batch codegen), MFMA, softmax ----
__global__ __launch_bounds__(256, 3)
void k_main(const float* __restrict__ data, const unsigned short* __restrict__ mubf,
            const float* __restrict__ mrs, const float* __restrict__ rstd,
            const float* __restrict__ mu2, const float* __restrict__ rtau,
            const float* __restrict__ ltau, const float* __restrict__ vldf,
            const int* __restrict__ idx, const int* __restrict__ ps,
            const int* __restrict__ cnt, const int* __restrict__ blk2cls,
            float* __restrict__ wpart)
{
    __shared__ float cst[512];                           // mrs[256] | rstd[256]
    __shared__ __align__(16) unsigned char Ub[64 * 512]; // bf16 mu tile, swizzled
    const int tid = threadIdx.x, w = tid >> 6, lane = tid & 63;
    const int g = blockIdx.x;
    const int slot0 = g * 64;
    const int padtot = ps[CNUM];
    if (slot0 >= padtot) { if (lane == 0) wpart[g * 4 + w] = 0.f; return; }
    const int c = blk2cls[g];
    const int relast = ps[c] + cnt[c] - 1;

    cst[tid] = mrs[tid];                                 // blockDim==256==DDIM
    cst[256 + tid] = rstd[tid];

    // ---- stage class-mu tile: 8 gload_lds per wave, 2 rows (1KB) each ----
    const int h2 = lane >> 5;
    const int m31b = 16 * (lane & 31);
#pragma unroll
    for (int pr = 0; pr < 8; ++pr) {
        const int lr = 16 * w + 2 * pr + h2;             // local mu row 0..63
        const int sw = 16 * (lr & 7);
        const unsigned char* sm = (const unsigned char*)mubf
            + ((size_t)c * KNUM + lr) * 512 + (m31b ^ sw);   // pre-swizzled source
        void* dm = (void*)(Ub + (size_t)(16 * w + 2 * pr) * 512);  // linear dest
        __builtin_amdgcn_global_load_lds(
            (const __attribute__((address_space(1))) void*)sm,
            (__attribute__((address_space(3))) void*)dm, 16, 0, 0);
    }

    // ---- X: one batch of 16 independent float4 loads (256B/lane in flight) ----
    const int n16 = lane & 15, kg = lane >> 4;
    const int slot = slot0 + 16 * w + n16;
    const int n = idx[min(slot, relast)];                // pads duplicate a real row
    const float* __restrict__ xr = data + (size_t)n * DDIM + 8 * kg;
    float4 u[16];
#pragma unroll
    for (int s = 0; s < 8; ++s) {
        u[2 * s]     = *(const float4*)(xr + 32 * s);
        u[2 * s + 1] = *(const float4*)(xr + 32 * s + 4);
    }
    asm volatile("s_waitcnt vmcnt(0)" ::: "memory");     // gload_lds complete; pins batch
    __syncthreads();                                     // Ub + cst visible

    // ---- normalize + pack from LDS constants ----
    const float* __restrict__ cm = &cst[8 * kg];
    const float* __restrict__ cr = &cst[256 + 8 * kg];
    short8 xb[8];
    float q = 0.f;
#pragma unroll
    for (int s = 0; s < 8; ++s) {
        const float4 u0 = u[2 * s], u1 = u[2 * s + 1];
        const float4 m0 = *(const float4*)(cm + 32 * s);
        const float4 m1 = *(const float4*)(cm + 32 * s + 4);
        const float4 r0 = *(const float4*)(cr + 32 * s);
        const float4 r1 = *(const float4*)(cr + 32 * s + 4);
        float a[8];
        a[0] = fmaf(u0.x, r0.x, -m0.x); a[1] = fmaf(u0.y, r0.y, -m0.y);
        a[2] = fmaf(u0.z, r0.z, -m0.z); a[3] = fmaf(u0.w, r0.w, -m0.w);
        a[4] = fmaf(u1.x, r1.x, -m1.x); a[5] = fmaf(u1.y, r1.y, -m1.y);
        a[6] = fmaf(u1.z, r1.z, -m1.z); a[7] = fmaf(u1.w, r1.w, -m1.w);
        union { short8 s8; __hip_bfloat162 b2[4]; } pk;
#pragma unroll
        for (int j = 0; j < 4; ++j) {
            q = fmaf(a[2 * j], a[2 * j], q);
            q = fmaf(a[2 * j + 1], a[2 * j + 1], q);
            pk.b2[j] = __float22bfloat162_rn(float2{a[2 * j], a[2 * j + 1]});
        }
        xb[s] = pk.s8;
    }
    q += shfl_xor_f(q, 16);
    q += shfl_xor_f(q, 32);

    // ---- MFMA: A = mu rows (k) from LDS, B = x; C[k][sample] ----
    const int Sb = 16 * (n16 & 7);
    f32x4 acc[4] = {};
#pragma unroll
    for (int s = 0; s < 8; ++s) {
        short8 af[4];
#pragma unroll
        for (int f = 0; f < 4; ++f)
            af[f] = *(const short8*)(Ub + (size_t)(16 * f + n16) * 512
                                        + ((64 * s + 16 * kg) ^ Sb));
#pragma unroll
        for (int f = 0; f < 4; ++f)
            acc[f] = __builtin_amdgcn_mfma_f32_16x16x32_bf16(af[f], xb[s], acc[f], 0, 0, 0);
    }

    // ---- epilogue: lane holds 16 k-values (k = 16f + 4kg + r) of its sample ----
    const int ckb = c * KNUM;
    float simv[16], lpv[16];
    float mxv = -3.4e38f;
#pragma unroll
    for (int f = 0; f < 4; ++f) {
        const int kb = ckb + 16 * f + 4 * kg;
        const float4 m2v = *(const float4*)(mu2 + kb);
        const float4 rtv = *(const float4*)(rtau + kb);
        const float4 ltv = *(const float4*)(ltau + kb);
        const float4 vlv = *(const float4*)(vldf + kb);
#pragma unroll
        for (int r = 0; r < 4; ++r) {
            const float m2 = (&m2v.x)[r];
            const float d2 = fmaxf(fmaf(-2.0f, acc[f][r], q + m2), 0.f);
            const float dist = -6.25f * sqrtf(d2);       // 100/sqrt(256)
            const float sim = ((&vlv.x)[r] > 0.5f) ? dist : -1.0e12f;
            simv[4 * f + r] = sim;
            lpv[4 * f + r] = fmaf(sim, (&rtv.x)[r], -(&ltv.x)[r]);
            mxv = fmaxf(mxv, 0.5f * sim);
        }
    }
    mxv = fmaxf(mxv, shfl_xor_f(mxv, 16));
    mxv = fmaxf(mxv, shfl_xor_f(mxv, 32));
    float se = 0.f, sl = 0.f;
#pragma unroll
    for (int i = 0; i < 16; ++i) {
        const float e = __expf(fmaf(0.5f, simv[i], -mxv));
        se += e;
        sl = fmaf(e, lpv[i], sl);
    }
    se += shfl_xor_f(se, 16); se += shfl_xor_f(se, 32);
    sl += shfl_xor_f(sl, 16); sl += shfl_xor_f(sl, 32);
    float res = (kg == 0 && slot <= relast) ? (-sl / se) : 0.f;
    res += shfl_xor_f(res, 1);
    res += shfl_xor_f(res, 2);
    res += shfl_xor_f(res, 4);
    res += shfl_xor_f(res, 8);
    if (lane == 0) wpart[g * 4 + w] = res;
}

// ---- K_D: deterministic per-class reduce -> loss (120 parallel accumulators) ----
__global__ void k_final(const float* __restrict__ wpart, const int* __restrict__ ps,
                        const int* __restrict__ cnt, float* __restrict__ out)
{
    __shared__ float part[120];
    __shared__ float seg[CNUM];
    const int t = threadIdx.x;
    if (t < 120) {
        const int c = t / 6, j = t % 6;
        float s = 0.f;
        const int b0 = ps[c] >> 6, b1 = ps[c + 1] >> 6;
        for (int b = b0 + j; b < b1; b += 6) {
            const float4 v = *(const float4*)(wpart + 4 * b);
            s += ((v.x + v.y) + (v.z + v.w));
        }
        part[t] = s;
    }
    __syncthreads();
    if (t < CNUM) {
        float s = 0.f;
#pragma unroll
        for (int j = 0; j < 6; ++j) s += part[t * 6 + j];
        seg[t] = s;
    }
    __syncthreads();
    if (t == 0) {
        float loss = 0.f;
        for (int c = 0; c < CNUM; c++) {
            const float cc = (float)cnt[c];
            if (cc > 0.f) loss += seg[c] / fmaxf(cc, 1.0f);
        }
        out[0] = loss;
    }
}

extern "C" void kernel_launch(void* const* d_in, const int* in_sizes, int n_in,
                              void* d_out, int out_size, void* d_ws, size_t ws_size,
                              hipStream_t stream)
{
    const float* data     = (const float*)d_in[0];
    const int*   labels   = (const int*)d_in[1];
    const float* mu       = (const float*)d_in[2];
    const float* exp_temp = (const float*)d_in[3];
    const float* med      = (const float*)d_in[4];
    const float* stdv     = (const float*)d_in[5];
    const float* runa     = (const float*)d_in[6];
    const float* runb     = (const float*)d_in[7];
    float* out = (float*)d_out;
    const int N = in_sizes[0] / DDIM;
    const int idx_slots = N + CNUM * 64;
    const int NB = (idx_slots + 63) / 64;

    char* w = (char*)d_ws;
    float* mu2  = (float*)w; w += (size_t)CNUM * KNUM * 4;
    float* rtau = (float*)w; w += (size_t)CNUM * KNUM * 4;
    float* ltau = (float*)w; w += (size_t)CNUM * KNUM * 4;
    float* vldf = (float*)w; w += (size_t)CNUM * KNUM * 4;
    float* rstd = (float*)w; w += (size_t)DDIM * 4;
    float* mrs  = (float*)w; w += (size_t)DDIM * 4;
    unsigned short* mubf = (unsigned short*)w; w += (size_t)CNUM * KNUM * DDIM * 2;
    int* bc  = (int*)w; w += (size_t)NHB * CNUM * 4;
    int* cnt = (int*)w; w += 64 * 4;
    int* ps  = (int*)w; w += 64 * 4;
    int* idx = (int*)w; w += (size_t)idx_slots * 4;
    int* blk2cls = (int*)w; w += (size_t)NB * 4;
    float* wp = (float*)w; w += (size_t)NB * 4 * 4;

    k_setup<<<dim3(384), dim3(256), 0, stream>>>(
        mu, exp_temp, runa, runb, med, stdv, labels, N,
        mu2, rtau, ltau, vldf, rstd, mrs, mubf, bc);
    k_scatter<<<dim3(NHB), dim3(256), 0, stream>>>(labels, N, bc, cnt, ps, blk2cls, idx);
    k_main<<<dim3(NB), dim3(256), 0, stream>>>(
        data, mubf, mrs, rstd, mu2, rtau, ltau, vldf, idx, ps, cnt, blk2cls, wp);
    k_final<<<dim3(1), dim3(128), 0, stream>>>(wp, ps, cnt, out);
}